// Round 14
// baseline (134.493 us; speedup 1.0000x reference)
//
#include <hip/hip_runtime.h>
#include <stdint.h>

#define INF    4096
#define OUTF   11008
#define NTOK   256
#define QZ_COLS (OUTF / 8)   // 1376
#define NTILES  (INF / 128)  // 32 K-tiles, one quant group each

#define BM 64
#define BN 32

typedef __attribute__((ext_vector_type(8))) _Float16 f16x8;
typedef __attribute__((ext_vector_type(2))) _Float16 f16x2;
typedef __attribute__((ext_vector_type(4))) float    f32x4;

typedef const __attribute__((address_space(1))) uint4 gl_uint4;
typedef __attribute__((address_space(3)))       uint4 sh_uint4;

// ---------------------------------------------------------------------------
// Pre-pass: x [256][4096] f32 -> xw f16 staged layout (d_ws, 2 MB):
//   xw[m_blk(4)][t(32)][k8(16)][mslot(64)], 16B = 8 f16,
//   word p = (col k8*8+p, k8*8+p+4), mslot holds row (mslot ^ (k8&7)).
// ---------------------------------------------------------------------------
__global__ __launch_bounds__(256, 2)
void xpack(const float* __restrict__ x, uint4* __restrict__ xw)
{
    const int g  = blockIdx.x * 256 + threadIdx.x;   // 131072 threads
    const int m  = g >> 9;
    const int c8 = g & 511;
    const int t  = c8 >> 4;
    const int k8 = c8 & 15;

    const float* src = x + (size_t)m * INF + c8 * 8;
    const f32x4 v0 = *(const f32x4*)src;
    const f32x4 v1 = *(const f32x4*)(src + 4);
    uint32_t d[4];
    #pragma unroll
    for (int p = 0; p < 4; ++p)
        d[p] = __builtin_bit_cast(uint32_t, __builtin_amdgcn_cvt_pkrtz(v0[p], v1[p]));

    const int mslot = (m & 63) ^ (k8 & 7);
    const size_t oi = ((size_t)(m >> 6) * 32 + t) * 1024 + k8 * 64 + mslot;
    xw[oi] = make_uint4(d[0], d[1], d[2], d[3]);
}

// ---------------------------------------------------------------------------
// GEMM. Anti-convoy: per-block K-group rotation (phase in {0,8,16,24}) so
// co-resident blocks are in different load/compute phases; K-sum order is
// block-deterministic, so results are exact-deterministic.
// ---------------------------------------------------------------------------
__global__ __launch_bounds__(256, 6)
void qlin_mfma(const uint4* __restrict__ xw,
               const float* __restrict__ scales,
               const float* __restrict__ bias,
               const int*   __restrict__ qweight,
               const int*   __restrict__ qzeros,
               float*       __restrict__ out)
{
    __shared__ uint4 A_sh[16][64];   // 16 KiB : [k8][mslot]
    __shared__ uint4 B_sh[16][32];   //  8 KiB : [k8][col]

    const int tid   = threadIdx.x;
    const int n0    = blockIdx.x * BN;
    const int m_blk = blockIdx.y;
    const int m0    = m_blk * BM;

    const int lane = tid & 63;
    const int wid  = tid >> 6;
    const int wm   = wid >> 1;   // 0..1 : 32-row slab
    const int wn   = wid & 1;    // 0..1 : 16-col slab
    const int l15  = lane & 15;
    const int l4   = lane >> 4;  // 0..3

    f32x4 acc[2] = { f32x4{0.f,0.f,0.f,0.f}, f32x4{0.f,0.f,0.f,0.f} };

    const int oL   = tid & 31;
    const int bk8  = tid >> 5;           // 0..7
    const int zsh  = (oL & 7) * 4;
    const int zcol = (n0 + oL) >> 3;

    const uint4* abase = xw + (size_t)m_blk * 32 * 1024;

    // phase: 4 groups, 8 tiles apart (L2 working set stays ~2.8 MB)
    const int phase = ((blockIdx.x * 7 + blockIdx.y * 11) & 3) << 3;

    // ---- prologue: reg-prefetch tile 'phase' ----
    uint32_t w0 = (uint32_t)qweight[(size_t)(phase * 16 + bk8)     * OUTF + n0 + oL];
    uint32_t w1 = (uint32_t)qweight[(size_t)(phase * 16 + bk8 + 8) * OUTF + n0 + oL];
    int   zw = qzeros[phase * QZ_COLS + zcol];
    float sf = scales[phase * OUTF + n0 + oL];

    for (int it = 0; it < NTILES; ++it) {
        const int t = (it + phase) & 31;

        // ---- A stage: 4 x global_load_lds (wave wid covers k8 = wid*4+r) ----
        #pragma unroll
        for (int r = 0; r < 4; ++r) {
            const int k8 = wid * 4 + r;
            const uint4* gp = abase + (size_t)t * 1024 + k8 * 64 + lane;
            __builtin_amdgcn_global_load_lds((gl_uint4*)gp, (sh_uint4*)&A_sh[k8][0],
                                             16, 0, 0);
        }

        // ---- B dequant from prefetched regs: ((q+1024)-(z+1024))*s ----
        const int z = ((zw >> zsh) & 15) + 1;
        const _Float16 hz = (_Float16)(float)(1024 + z);
        const f16x2 z2 = {hz, hz};
        const _Float16 hs = (_Float16)sf;
        const f16x2 s2 = {hs, hs};
        uint32_t d0[4], d1[4];
        #pragma unroll
        for (int p = 0; p < 4; ++p) {
            const uint32_t b0 = ((w0 >> (4 * p)) & 0x000F000Fu) | 0x64006400u;
            const uint32_t b1 = ((w1 >> (4 * p)) & 0x000F000Fu) | 0x64006400u;
            d0[p] = __builtin_bit_cast(uint32_t,
                        (__builtin_bit_cast(f16x2, b0) - z2) * s2);
            d1[p] = __builtin_bit_cast(uint32_t,
                        (__builtin_bit_cast(f16x2, b1) - z2) * s2);
        }
        *(uint4*)&B_sh[bk8][oL]     = make_uint4(d0[0], d0[1], d0[2], d0[3]);
        *(uint4*)&B_sh[bk8 + 8][oL] = make_uint4(d1[0], d1[1], d1[2], d1[3]);

        __syncthreads();   // drains vmcnt (gll) + lgkmcnt (ds_write)

        // ---- issue next tile's reg loads (overlap with compute below) ----
        if (it + 1 < NTILES) {
            const int tn = (it + 1 + phase) & 31;
            w0 = (uint32_t)qweight[(size_t)(tn * 16 + bk8)     * OUTF + n0 + oL];
            w1 = (uint32_t)qweight[(size_t)(tn * 16 + bk8 + 8) * OUTF + n0 + oL];
            zw = qzeros[tn * QZ_COLS + zcol];
            sf = scales[tn * OUTF + n0 + oL];
        }

        // ---- compute: 4 k-steps, 2 MFMA each ----
        #pragma unroll
        for (int kk = 0; kk < 4; ++kk) {
            const int k8 = kk * 4 + l4;
            const f16x8 a0 = __builtin_bit_cast(f16x8, A_sh[k8][(wm * 32      + l15) ^ (k8 & 7)]);
            const f16x8 a1 = __builtin_bit_cast(f16x8, A_sh[k8][(wm * 32 + 16 + l15) ^ (k8 & 7)]);
            const f16x8 b  = __builtin_bit_cast(f16x8, B_sh[k8][wn * 16 + l15]);
            acc[0] = __builtin_amdgcn_mfma_f32_16x16x32_f16(a0, b, acc[0], 0, 0, 0);
            acc[1] = __builtin_amdgcn_mfma_f32_16x16x32_f16(a1, b, acc[1], 0, 0, 0);
        }

        __syncthreads();
    }

    // ---- epilogue: row=(lane>>4)*4+reg, col=lane&15 ----
    const int col = n0 + wn * 16 + l15;
    const float bv = bias[col];
    #pragma unroll
    for (int i = 0; i < 2; ++i) {
        const int row0 = m0 + wm * 32 + i * 16 + l4 * 4;
        #pragma unroll
        for (int r = 0; r < 4; ++r)
            out[(size_t)(row0 + r) * OUTF + col] = acc[i][r] + bv;
    }
}

extern "C" void kernel_launch(void* const* d_in, const int* in_sizes, int n_in,
                              void* d_out, int out_size, void* d_ws, size_t ws_size,
                              hipStream_t stream)
{
    const float* x       = (const float*)d_in[0];
    const float* scales  = (const float*)d_in[1];
    const float* bias    = (const float*)d_in[2];
    const int*   qweight = (const int*)d_in[3];
    const int*   qzeros  = (const int*)d_in[4];
    // d_in[5] = g_idx : deterministic (i // 128), not needed on device
    float* out = (float*)d_out;
    uint4* xw  = (uint4*)d_ws;   // 2 MiB staged-f16 copy of x

    xpack<<<dim3(512), dim3(256), 0, stream>>>(x, xw);
    dim3 grid(OUTF / BN, NTOK / BM);  // (344, 4) = 1376 blocks, ~5.4/CU
    qlin_mfma<<<grid, dim3(256), 0, stream>>>(xw, scales, bias, qweight, qzeros, out);
}